// Round 6
// baseline (187.410 us; speedup 1.0000x reference)
//
#include <hip/hip_runtime.h>

// GraphAugmentation fused kernel, MI355X — R6: single-kernel MFMA, fp16
// activations + dual-fp16 weights, shfl-based hidden redistribution.
//
// Algebra:
//  * softmax over 8 identical affinities == 1/8 -> Q/K/attn dead.
//  * u = [xc ; xavg] (K=32), xavg = mean of 8 rolls of x.
//  * agg    = [0|mw] @ u + mb                                  (16x32)
//  * hidden = relu(W1' @ u + b1'), W1' = [g1w_x | g1w_a@mw],
//             b1' = g1b + g1w_a@mb                             (32x32)
//  * gate   = sigmoid(g2w @ hidden + g2b)                      (16x32)
//  * out    = agg * gate
//
// R6 vs R5 (71us main: 23% occ from 40KB LDS, 5.2M bank-conflict from h
// half2 writes, 3 serializing fences/group, +~15us prep launch):
//  * activations single fp16 (err ~5e-4 << 2^-8 budget), weights hi+lo
//    -> 2 MFMA per GEMM (32/wave), u-staging 16KB, no lo-split VALU.
//  * hidden redistributed via 8 __shfl + 4 selects (no h LDS, no fences,
//    no conflict-prone half2 scatter).
//  * W1'/b1' staged per-block cooperatively (one __syncthreads); single
//    kernel, no d_ws, no second launch.
//  * no inline-asm fences; compiler-managed lgkmcnt; groups fully
//    unrolled with all 4 u B-frags prefetched.

#define HW 262144   // 512*512

typedef _Float16 half8  __attribute__((ext_vector_type(8)));
typedef _Float16 half2v __attribute__((ext_vector_type(2)));
typedef float    f32x4  __attribute__((ext_vector_type(4)));
typedef int      int4v  __attribute__((ext_vector_type(4)));

#define MFMA16(A, B, C) __builtin_amdgcn_mfma_f32_16x16x32_f16((A), (B), (C), 0, 0, 0)

__global__ __launch_bounds__(256) void ga_main(
    const float* __restrict__ x,
    const float* __restrict__ mw,  const float* __restrict__ mb,
    const float* __restrict__ g1w, const float* __restrict__ g1b,
    const float* __restrict__ g2w, const float* __restrict__ g2b,
    float* __restrict__ out)
{
  constexpr int DY[8] = {-4, -4, -4, -3, -2, 2, 3, 4};
  constexpr int DX[8] = {-4, -1,  2,  4, -3, 3, -2, 4};

  __shared__ _Float16 u_s[4 * 64 * 32];  // 16 KB: per-wave u staging
  __shared__ float    w1a[32 * 16];      //  2 KB: W1' columns k>=16
  __shared__ float    b1s[32];           // b1' = g1b + g1w_a @ mb

  const int tid  = threadIdx.x;
  const int wv   = tid >> 6, lane = tid & 63;
  const int q    = lane >> 4, m = lane & 15;

  // ---- block-cooperative prep: W1'a[j][c] and b1'[j] into LDS ----
  for (int idx = tid; idx < 512; idx += 256) {
    const int j = idx >> 4, c = idx & 15;
    float s = 0.f;
#pragma unroll
    for (int t2 = 0; t2 < 16; ++t2)
      s += g1w[j * 32 + 16 + t2] * mw[t2 * 16 + c];
    w1a[idx] = s;
  }
  if (tid < 32) {
    float s = g1b[tid];
#pragma unroll
    for (int t2 = 0; t2 < 16; ++t2)
      s += g1w[tid * 32 + 16 + t2] * mb[t2];
    b1s[tid] = s;
  }
  __syncthreads();

  // ---- per-lane weight A-fragments (fp16 hi+lo), element e <-> k=8q+e ----
  half8 aAg_h, aAg_l, aH0_h, aH0_l, aH1_h, aH1_l, aG2_h, aG2_l;
#pragma unroll
  for (int e = 0; e < 8; ++e) {
    const int kk = 8 * q + e;
    float v0 = 0.f;
    if (kk >= 16) v0 = mw[m * 16 + (kk - 16)];      // Abar = [0 | mw]
    _Float16 h = (_Float16)v0;
    aAg_h[e] = h; aAg_l[e] = (_Float16)(v0 - (float)h);

    float v1, v2;
    if (q < 2) { v1 = g1w[m * 32 + kk];        v2 = g1w[(16 + m) * 32 + kk]; }
    else       { v1 = w1a[m * 16 + (kk - 16)]; v2 = w1a[(16 + m) * 16 + (kk - 16)]; }
    h = (_Float16)v1; aH0_h[e] = h; aH0_l[e] = (_Float16)(v1 - (float)h);
    h = (_Float16)v2; aH1_h[e] = h; aH1_l[e] = (_Float16)(v2 - (float)h);

    const float v3 = g2w[m * 32 + kk];
    h = (_Float16)v3; aG2_h[e] = h; aG2_l[e] = (_Float16)(v3 - (float)h);
  }
  f32x4 bias0, bias1, bias2, bias3;
#pragma unroll
  for (int rg = 0; rg < 4; ++rg) {
    bias0[rg] = mb[4 * q + rg];
    bias1[rg] = b1s[4 * q + rg];
    bias2[rg] = b1s[16 + 4 * q + rg];
    bias3[rg] = g2b[4 * q + rg];
  }

  // ---- XCD-aware bijective swizzle (proven: FETCH 207->34 MB) ----
  const int swz = ((blockIdx.x & 7) << 9) | (blockIdx.x >> 3);
  const int b   = swz >> 10;
  const int rem = swz & 1023;
  const int row = rem >> 1;
  const int colbase = ((rem & 1) << 8) + wv * 64;
  const int cw  = colbase + lane;

  const float* xb = x + b * 16 * HW;
  unsigned off[8];
#pragma unroll
  for (int i = 0; i < 8; ++i)
    off[i] = ((row - DY[i]) & 511) * 512 + ((cw - DX[i]) & 511);
  const unsigned ctr = row * 512 + cw;

  // ---- gathers: xc (center), xa (mean of 8 rolls) ----
  float xc[16], xa[16];
#pragma unroll
  for (int c = 0; c < 16; ++c) {
    const float* xp = xb + c * HW;
    xc[c] = xp[ctr];
    float s = 0.f;
#pragma unroll
    for (int i = 0; i < 8; ++i) s += xp[off[i]];
    xa[c] = s * 0.125f;
  }

  // ---- pack u=[xc;xa] to fp16 and stage (wave-private, chunk-XOR swizzle) ----
  _Float16* ub = u_s + (wv * 64 + lane) * 32;
#pragma unroll
  for (int j = 0; j < 4; ++j) {
    half8 v;
#pragma unroll
    for (int e = 0; e < 8; ++e) {
      const int k = j * 8 + e;
      v[e] = (_Float16)((k < 16) ? xc[k] : xa[k - 16]);
    }
    *(half8*)(ub + ((j ^ (lane & 3)) << 3)) = v;
  }

  // ---- prefetch all 4 u B-fragments (compiler inserts lgkmcnt) ----
  const _Float16* ubase = u_s + wv * 64 * 32;
  half8 bf[4];
#pragma unroll
  for (int g = 0; g < 4; ++g)
    bf[g] = *(const half8*)(ubase + (g * 16 + m) * 32 + ((q ^ (m & 3)) << 3));

  float* ob = out + b * 16 * HW + row * 512 + colbase;
  const f32x4 z = {0.f, 0.f, 0.f, 0.f};
  const int s0 = m + 32 * (q & 1);   // shfl sources for hidden redistribution
  const int s1 = s0 + 16;

#pragma unroll
  for (int g = 0; g < 4; ++g) {
    // agg / hidden GEMMs: (Ahi+Alo) @ B, B single fp16
    f32x4 acc_a  = MFMA16(aAg_l, bf[g], z);
    acc_a        = MFMA16(aAg_h, bf[g], acc_a);
    f32x4 acc_h0 = MFMA16(aH0_l, bf[g], z);
    acc_h0       = MFMA16(aH0_h, bf[g], acc_h0);
    f32x4 acc_h1 = MFMA16(aH1_l, bf[g], z);
    acc_h1       = MFMA16(aH1_h, bf[g], acc_h1);

    // relu + fp16 pack: this lane holds h ch {4q+rg} (P) and {16+4q+rg} (Q) of px m
    half2v ph0, ph1, qh0, qh1;
    ph0[0] = (_Float16)fmaxf(acc_h0[0] + bias1[0], 0.f);
    ph0[1] = (_Float16)fmaxf(acc_h0[1] + bias1[1], 0.f);
    ph1[0] = (_Float16)fmaxf(acc_h0[2] + bias1[2], 0.f);
    ph1[1] = (_Float16)fmaxf(acc_h0[3] + bias1[3], 0.f);
    qh0[0] = (_Float16)fmaxf(acc_h1[0] + bias2[0], 0.f);
    qh0[1] = (_Float16)fmaxf(acc_h1[1] + bias2[1], 0.f);
    qh1[0] = (_Float16)fmaxf(acc_h1[2] + bias2[2], 0.f);
    qh1[1] = (_Float16)fmaxf(acc_h1[3] + bias2[3], 0.f);
    const int P0 = __builtin_bit_cast(int, ph0);
    const int P1 = __builtin_bit_cast(int, ph1);
    const int Q0 = __builtin_bit_cast(int, qh0);
    const int Q1 = __builtin_bit_cast(int, qh1);

    // redistribute to gate-B layout: lane (q,m) needs h ch 8q..8q+7 of px m
    const int t0 = __shfl(P0, s0), t1 = __shfl(P1, s0);
    const int t2 = __shfl(P0, s1), t3 = __shfl(P1, s1);
    const int v0 = __shfl(Q0, s0), v1 = __shfl(Q1, s0);
    const int v2 = __shfl(Q0, s1), v3 = __shfl(Q1, s1);
    int4v gd;
    gd.x = (q < 2) ? t0 : v0;
    gd.y = (q < 2) ? t1 : v1;
    gd.z = (q < 2) ? t2 : v2;
    gd.w = (q < 2) ? t3 : v3;
    const half8 gB = __builtin_bit_cast(half8, gd);

    f32x4 acc_g = MFMA16(aG2_l, gB, z);
    acc_g       = MFMA16(aG2_h, gB, acc_g);

    // epilogue: out = (agg+mb) * sigmoid(gate_pre + g2b)
#pragma unroll
    for (int rg = 0; rg < 4; ++rg) {
      const float ag = acc_a[rg] + bias0[rg];
      const float gp = acc_g[rg] + bias3[rg];
      const float gt = __builtin_amdgcn_rcpf(1.f + __expf(-gp));
      ob[(4 * q + rg) * HW + g * 16 + m] = ag * gt;
    }
  }
}

extern "C" void kernel_launch(void* const* d_in, const int* in_sizes, int n_in,
                              void* d_out, int out_size, void* d_ws, size_t ws_size,
                              hipStream_t stream) {
  // setup_inputs() order:
  // 0:x 1:qw 2:qb 3:kw 4:kb 5:mw 6:mb 7:scaling 8:g1w 9:g1b 10:g2w 11:g2b
  const float* x   = (const float*)d_in[0];
  const float* mw  = (const float*)d_in[5];
  const float* mb  = (const float*)d_in[6];
  const float* g1w = (const float*)d_in[8];
  const float* g1b = (const float*)d_in[9];
  const float* g2w = (const float*)d_in[10];
  const float* g2b = (const float*)d_in[11];
  float* out = (float*)d_out;

  // 4096 wgs x 256 thr; wave = 64 px of one image row.
  ga_main<<<4096, 256, 0, stream>>>(x, mw, mb, g1w, g1b, g2w, g2b, out);
}